// Round 9
// baseline (764.995 us; speedup 1.0000x reference)
//
#include <hip/hip_runtime.h>

typedef unsigned int uint;
typedef unsigned short ushort;
typedef short sv8 __attribute__((ext_vector_type(8)));     // 8 bf16 (4 VGPR)
typedef float f32x4 __attribute__((ext_vector_type(4)));
typedef ushort u16x8 __attribute__((ext_vector_type(8)));

__device__ __forceinline__ ushort f2b(float f) {  // fp32 -> bf16 RN (scalar path)
  uint u = __float_as_uint(f);
  return (ushort)((u + 0x7FFFu + ((u >> 16) & 1u)) >> 16);
}
__device__ __forceinline__ float b2f_lo(uint p) { return __uint_as_float(p << 16); }
__device__ __forceinline__ float b2f_hi(uint p) { return __uint_as_float(p & 0xFFFF0000u); }
__device__ __forceinline__ uint cvtpk(float lo, float hi) {  // packed f32->bf16x2 RNE
  uint r;
  asm("v_cvt_pk_bf16_f32 %0, %1, %2" : "=v"(r) : "v"(lo), "v"(hi));
  return r;
}

#define MFMA16(acc, a, b) \
  asm volatile("v_mfma_f32_16x16x32_bf16 %0, %1, %2, %0" : "+v"(acc) : "v"(a), "v"(b))

// ================= bucketed CSR build (single histogram pass) =================
// bucket = dst >> 10 (1024 nodes/bucket). NB <= 256. chunk per block = 16384 edges.

__global__ __launch_bounds__(256) void k_hist1(const int* __restrict__ dst,
                                               int* __restrict__ counts, int E) {
  __shared__ int h[256];
  int t = threadIdx.x;
  h[t] = 0;
  __syncthreads();
#pragma unroll
  for (int i = 0; i < 16; ++i) {
    int idx = blockIdx.x * 16384 + i * 1024 + t * 4;
    if (idx + 4 <= E) {
      int4 d = *(const int4*)&dst[idx];
      atomicAdd(&h[d.x >> 10], 1);
      atomicAdd(&h[d.y >> 10], 1);
      atomicAdd(&h[d.z >> 10], 1);
      atomicAdd(&h[d.w >> 10], 1);
    } else {
      for (int k = 0; k < 4; ++k)
        if (idx + k < E) atomicAdd(&h[dst[idx + k] >> 10], 1);
    }
  }
  __syncthreads();
  counts[blockIdx.x * 256 + t] = h[t];
}

// column scan over blocks (in-place: counts -> per-block exclusive offsets),
// plus bucket bases / totals. One block of 256 threads; thread b owns bucket b.
__global__ __launch_bounds__(256) void k_colscan(int* __restrict__ counts,
                                                 int* __restrict__ bbase,
                                                 int* __restrict__ btot,
                                                 int* __restrict__ rowptr,
                                                 int NBLK, int N, int E) {
  __shared__ int s[256];
  int b = threadIdx.x;
  int run = 0;
#pragma unroll 4
  for (int blk = 0; blk < NBLK; ++blk) {
    int v = counts[blk * 256 + b];
    counts[blk * 256 + b] = run;
    run += v;
  }
  s[b] = run;
  __syncthreads();
  for (int off = 1; off < 256; off <<= 1) {
    int u = (b >= off) ? s[b - off] : 0;
    __syncthreads();
    s[b] += u;
    __syncthreads();
  }
  bbase[b] = s[b] - run;
  btot[b] = run;
  if (b == 0) rowptr[N] = E;
}

// keyval packing: src(bits 0..16) | (dst & 1023)(bits 17..26)  [N < 131072]
__global__ __launch_bounds__(256) void k_scatter(const int* __restrict__ ei,
                                                 const int* __restrict__ counts,
                                                 const int* __restrict__ bbase,
                                                 uint* __restrict__ keyval, int E) {
  __shared__ int h[256];
  __shared__ int base[256];
  int t = threadIdx.x;
  base[t] = bbase[t] + counts[blockIdx.x * 256 + t];
  h[t] = 0;
  __syncthreads();
#pragma unroll
  for (int i = 0; i < 16; ++i) {
    int idx = blockIdx.x * 16384 + i * 1024 + t * 4;
    if (idx + 4 <= E) {
      int4 sv = *(const int4*)&ei[idx];
      int4 dv = *(const int4*)&ei[E + idx];
      int b0 = dv.x >> 10, b1 = dv.y >> 10, b2 = dv.z >> 10, b3 = dv.w >> 10;
      int r0 = atomicAdd(&h[b0], 1);
      keyval[base[b0] + r0] = (uint)sv.x | (((uint)dv.x & 1023u) << 17);
      int r1 = atomicAdd(&h[b1], 1);
      keyval[base[b1] + r1] = (uint)sv.y | (((uint)dv.y & 1023u) << 17);
      int r2 = atomicAdd(&h[b2], 1);
      keyval[base[b2] + r2] = (uint)sv.z | (((uint)dv.z & 1023u) << 17);
      int r3 = atomicAdd(&h[b3], 1);
      keyval[base[b3] + r3] = (uint)sv.w | (((uint)dv.w & 1023u) << 17);
    } else {
      for (int k = 0; k < 4; ++k)
        if (idx + k < E) {
          int sv = ei[idx + k], dv = ei[E + idx + k];
          int b = dv >> 10;
          int r = atomicAdd(&h[b], 1);
          keyval[base[b] + r] = (uint)sv | (((uint)dv & 1023u) << 17);
        }
    }
  }
}

// one block per bucket: per-node counts, local scan, rowptr/dinv(f32+bf16), col scatter
__global__ __launch_bounds__(1024) void k_build(const uint* __restrict__ keyval,
                                                const int* __restrict__ bbase,
                                                const int* __restrict__ btot,
                                                int* __restrict__ rowptr,
                                                float* __restrict__ dinv,
                                                ushort* __restrict__ dinvb,
                                                int* __restrict__ col, int N) {
  __shared__ int c[1024];
  int b = blockIdx.x, t = threadIdx.x;
  int ebase = bbase[b], ecnt = btot[b];
  int node0 = b << 10;
  c[t] = 0;
  __syncthreads();
  for (int i = t; i < ecnt; i += 1024)
    atomicAdd(&c[keyval[ebase + i] >> 17], 1);
  __syncthreads();
  int v = c[t];
  for (int off = 1; off < 1024; off <<= 1) {
    int u = (t >= off) ? c[t - off] : 0;
    __syncthreads();
    c[t] += u;
    __syncthreads();
  }
  int excl = c[t] - v;
  int node = node0 + t;
  if (node < N) {
    float dv = rsqrtf((float)(v + 1));  // GCN degree incl self-loop
    rowptr[node] = ebase + excl;
    dinv[node] = dv;
    dinvb[node] = f2b(dv);
  }
  __syncthreads();
  c[t] = excl;
  __syncthreads();
  for (int i = t; i < ecnt; i += 1024) {
    uint kv = keyval[ebase + i];
    int r = atomicAdd(&c[kv >> 17], 1);
    col[ebase + r] = (int)(kv & 0x1FFFFu);
  }
}

// ====== GEMM1: Hb(bf16) = feat(fp32) @ W1^T; 256 rows/block, 64 rows/wave ======

__global__ __launch_bounds__(256) void k_gemm1(const float* __restrict__ A,
                                               const float* __restrict__ W,
                                               ushort* __restrict__ Hb, int N) {
  __shared__ __align__(16) ushort smem[17408];  // W tile 32KB; epilogue 4x[16][136]
  int t = threadIdx.x;
#pragma unroll
  for (int i = 0; i < 8; ++i) {
    int c_ = t + i * 256;
    int row = c_ >> 4, slot = c_ & 15;
    const float* wp = &W[row * 128 + slot * 8];
    float4 w0 = *(const float4*)wp;
    float4 w1 = *(const float4*)(wp + 4);
    uint4 v = make_uint4(cvtpk(w0.x, w0.y), cvtpk(w0.z, w0.w),
                         cvtpk(w1.x, w1.y), cvtpk(w1.z, w1.w));
    *(uint4*)&smem[row * 128 + ((slot ^ (row & 7)) << 3)] = v;
  }
  __syncthreads();

  int wv = t >> 6, l = t & 63;
  int lr = l & 15, lk = l >> 4;
  int r0 = blockIdx.x * 256 + wv * 64;
  f32x4 acc[4][8];
#pragma unroll
  for (int rb = 0; rb < 4; ++rb)
#pragma unroll
    for (int ct = 0; ct < 8; ++ct) acc[rb][ct] = (f32x4){0.f, 0.f, 0.f, 0.f};

#pragma unroll
  for (int kk = 0; kk < 4; ++kk) {
    sv8 af[4];
#pragma unroll
    for (int rb = 0; rb < 4; ++rb) {
      int r = r0 + rb * 16 + lr;
      if (r >= N) r = N - 1;
      const float* ap = &A[(size_t)r * 128 + kk * 32 + lk * 8];
      float4 a0 = *(const float4*)ap;
      float4 a1 = *(const float4*)(ap + 4);
      uint4 au = make_uint4(cvtpk(a0.x, a0.y), cvtpk(a0.z, a0.w),
                            cvtpk(a1.x, a1.y), cvtpk(a1.z, a1.w));
      af[rb] = *(sv8*)&au;
    }
#pragma unroll
    for (int ct = 0; ct < 8; ++ct) {
      int brow = ct * 16 + lr;
      sv8 bf = *(const sv8*)&smem[brow * 128 + (((kk * 4 + lk) ^ (brow & 7)) << 3)];
      MFMA16(acc[0][ct], af[0], bf);
      MFMA16(acc[1][ct], af[1], bf);
      MFMA16(acc[2][ct], af[2], bf);
      MFMA16(acc[3][ct], af[3], bf);
    }
  }
  asm volatile("s_nop 7\n\ts_nop 7");
  __syncthreads();  // protect W tile until all waves done
  ushort* ep = smem + wv * (16 * 136);
#pragma unroll
  for (int rb = 0; rb < 4; ++rb) {
#pragma unroll
    for (int ct = 0; ct < 8; ++ct)
#pragma unroll
      for (int i = 0; i < 4; ++i)
        ep[(lk * 4 + i) * 136 + ct * 16 + lr] = f2b(acc[rb][ct][i]);
#pragma unroll
    for (int it = 0; it < 2; ++it) {
      int row = it * 8 + (l >> 3);
      int gr = r0 + rb * 16 + row;
      if (gr < N) {
#pragma unroll
        for (int cc = 0; cc < 2; ++cc) {
          int colv = cc * 64 + (l & 7) * 8;
          *(u16x8*)&Hb[(size_t)gr * 128 + colv] = *(const u16x8*)&ep[row * 136 + colv];
        }
      }
    }
  }
}

// == GEMM2: Out = relu(mean@Wl^T + x1@Wr^T + bl); 256 rows/block, 64 rows/wave ==

__global__ __launch_bounds__(256) void k_gemm2(const ushort* __restrict__ Mb,
                                               const ushort* __restrict__ X1b,
                                               const float* __restrict__ Wl,
                                               const float* __restrict__ Wr,
                                               const float* __restrict__ bl,
                                               float* __restrict__ Out, int N) {
  __shared__ __align__(16) ushort smem[2 * 128 * 128];  // 64KB; epilogue reuses 33.8KB
  int t = threadIdx.x;
#pragma unroll
  for (int i = 0; i < 8; ++i) {
    int c_ = t + i * 256;
    int row = c_ >> 4, slot = c_ & 15;
    int off = (slot ^ (row & 7)) << 3;
    {
      const float* wp = &Wl[row * 128 + slot * 8];
      float4 w0 = *(const float4*)wp;
      float4 w1 = *(const float4*)(wp + 4);
      *(uint4*)&smem[row * 128 + off] =
          make_uint4(cvtpk(w0.x, w0.y), cvtpk(w0.z, w0.w),
                     cvtpk(w1.x, w1.y), cvtpk(w1.z, w1.w));
    }
    {
      const float* wp = &Wr[row * 128 + slot * 8];
      float4 w0 = *(const float4*)wp;
      float4 w1 = *(const float4*)(wp + 4);
      *(uint4*)&smem[16384 + row * 128 + off] =
          make_uint4(cvtpk(w0.x, w0.y), cvtpk(w0.z, w0.w),
                     cvtpk(w1.x, w1.y), cvtpk(w1.z, w1.w));
    }
  }
  __syncthreads();

  int wv = t >> 6, l = t & 63;
  int lr = l & 15, lk = l >> 4;
  int r0 = blockIdx.x * 256 + wv * 64;
  f32x4 acc[4][8];
#pragma unroll
  for (int rb = 0; rb < 4; ++rb)
#pragma unroll
    for (int ct = 0; ct < 8; ++ct) acc[rb][ct] = (f32x4){0.f, 0.f, 0.f, 0.f};

#pragma unroll
  for (int ph = 0; ph < 2; ++ph) {
    const ushort* Ab = ph ? X1b : Mb;
    const ushort* Wp = smem + ph * 16384;
#pragma unroll
    for (int kk = 0; kk < 4; ++kk) {
      sv8 af[4];
#pragma unroll
      for (int rb = 0; rb < 4; ++rb) {
        int r = r0 + rb * 16 + lr;
        if (r >= N) r = N - 1;
        af[rb] = *(const sv8*)&Ab[(size_t)r * 128 + kk * 32 + lk * 8];
      }
#pragma unroll
      for (int ct = 0; ct < 8; ++ct) {
        int brow = ct * 16 + lr;
        sv8 bf = *(const sv8*)&Wp[brow * 128 + (((kk * 4 + lk) ^ (brow & 7)) << 3)];
        MFMA16(acc[0][ct], af[0], bf);
        MFMA16(acc[1][ct], af[1], bf);
        MFMA16(acc[2][ct], af[2], bf);
        MFMA16(acc[3][ct], af[3], bf);
      }
    }
  }
  asm volatile("s_nop 7\n\ts_nop 7");
  __syncthreads();
  float* epf = (float*)smem + wv * (16 * 132);
  float bb[8];
#pragma unroll
  for (int ct = 0; ct < 8; ++ct) bb[ct] = bl[ct * 16 + lr];
#pragma unroll
  for (int rb = 0; rb < 4; ++rb) {
#pragma unroll
    for (int ct = 0; ct < 8; ++ct)
#pragma unroll
      for (int i = 0; i < 4; ++i)
        epf[(lk * 4 + i) * 132 + ct * 16 + lr] = fmaxf(acc[rb][ct][i] + bb[ct], 0.f);
#pragma unroll
    for (int it = 0; it < 2; ++it) {
      int row = it * 8 + (l >> 3);
      int gr = r0 + rb * 16 + row;
      if (gr < N) {
#pragma unroll
        for (int cc = 0; cc < 4; ++cc) {
          int colv = cc * 32 + (l & 7) * 4;
          *(float4*)&Out[(size_t)gr * 128 + colv] = *(const float4*)&epf[row * 132 + colv];
        }
      }
    }
  }
}

// ========== XCD-sliced aggregations ==========
// slice = blockIdx.x & 7 (rides blockIdx->XCD round-robin): each XCD gathers only a
// 16-feature (32 B) column slice -> 3.2 MB working set fits its private 4 MiB L2.
// Wave per node; 32 row-slots x 2 lanes (uint4 = 8 features each).
// packed = src_idx(0..16) | bf16_weight_no-sign(17..31).
// NOTE: __shfl must be OUTSIDE the r<m guard — ds_bpermute returns 0 when the
// SOURCE lane's exec bit is 0 (round-8 bug: dropped edges for deg in (32,64]).

#define AGG_SLICE_LOOP(SRC)                                                   \
  for (int j0 = s0; j0 < s1; j0 += 64) {                                      \
    int rem = s1 - j0;                                                        \
    uint packed = 0;                                                          \
    if (l < rem) {                                                            \
      int ix = col[j0 + l];                                                   \
      packed = (uint)ix | (WEIGHT(ix) << 17);                                 \
    }                                                                         \
    int m = rem < 64 ? rem : 64;                                              \
    for (int jj = 0; jj < m; jj += 32) {                                      \
      int r = jj + q2;                                                        \
      uint pa = (uint)__shfl((int)packed, r);  /* all 64 lanes execute */     \
      if (r < m) {                                                            \
        float wa = __uint_as_float((pa >> 17) << 16);                         \
        uint4 v = *(const uint4*)&SRC[(size_t)(pa & 0x1FFFFu) * 128];         \
        acc[0] = fmaf(b2f_lo(v.x), wa, acc[0]);                               \
        acc[1] = fmaf(b2f_hi(v.x), wa, acc[1]);                               \
        acc[2] = fmaf(b2f_lo(v.y), wa, acc[2]);                               \
        acc[3] = fmaf(b2f_hi(v.y), wa, acc[3]);                               \
        acc[4] = fmaf(b2f_lo(v.z), wa, acc[4]);                               \
        acc[5] = fmaf(b2f_hi(v.z), wa, acc[5]);                               \
        acc[6] = fmaf(b2f_lo(v.w), wa, acc[6]);                               \
        acc[7] = fmaf(b2f_hi(v.w), wa, acc[7]);                               \
      }                                                                       \
    }                                                                         \
  }                                                                           \
  _Pragma("unroll")                                                           \
  for (int k = 0; k < 8; ++k) {                                               \
    acc[k] += __shfl_xor(acc[k], 2);                                          \
    acc[k] += __shfl_xor(acc[k], 4);                                          \
    acc[k] += __shfl_xor(acc[k], 8);                                          \
    acc[k] += __shfl_xor(acc[k], 16);                                         \
    acc[k] += __shfl_xor(acc[k], 32);                                         \
  }

__global__ __launch_bounds__(512) void k_agg_gcn_s(const ushort* __restrict__ Hb,
                                                   const int* __restrict__ rowptr,
                                                   const int* __restrict__ col,
                                                   const float* __restrict__ dinv,
                                                   const ushort* __restrict__ dinvb,
                                                   const float* __restrict__ bias,
                                                   ushort* __restrict__ X1b, int N) {
  int slice = blockIdx.x & 7;
  int wid = (blockIdx.x >> 3) * 8 + (threadIdx.x >> 6);
  int l = threadIdx.x & 63;
  if (wid >= N) return;
  int q2 = l >> 1, lc2 = l & 1;
  int fo = slice * 16 + lc2 * 8;                 // this lane's 8-feature offset
  const ushort* Hs = Hb + fo;
  float acc[8] = {0.f, 0.f, 0.f, 0.f, 0.f, 0.f, 0.f, 0.f};
  int s0 = rowptr[wid], s1 = rowptr[wid + 1];
#define WEIGHT(ix) ((uint)dinvb[ix])
  AGG_SLICE_LOOP(Hs)
#undef WEIGHT
  if (q2 == 0) {
    float di = dinv[wid];
    uint4 hv = *(const uint4*)&Hs[(size_t)wid * 128];
    float4 b0 = *(const float4*)&bias[fo];
    float4 b1 = *(const float4*)&bias[fo + 4];
    float hvf[8] = {b2f_lo(hv.x), b2f_hi(hv.x), b2f_lo(hv.y), b2f_hi(hv.y),
                    b2f_lo(hv.z), b2f_hi(hv.z), b2f_lo(hv.w), b2f_hi(hv.w)};
    float bb[8] = {b0.x, b0.y, b0.z, b0.w, b1.x, b1.y, b1.z, b1.w};
    float o[8];
#pragma unroll
    for (int k = 0; k < 8; ++k)
      o[k] = fmaxf((acc[k] + hvf[k] * di) * di + bb[k], 0.f);
    uint4 r = make_uint4(cvtpk(o[0], o[1]), cvtpk(o[2], o[3]),
                         cvtpk(o[4], o[5]), cvtpk(o[6], o[7]));
    *(uint4*)&X1b[(size_t)wid * 128 + fo] = r;
  }
}

__global__ __launch_bounds__(512) void k_agg_mean_s(const ushort* __restrict__ Xb,
                                                    const int* __restrict__ rowptr,
                                                    const int* __restrict__ col,
                                                    ushort* __restrict__ Mb, int N) {
  int slice = blockIdx.x & 7;
  int wid = (blockIdx.x >> 3) * 8 + (threadIdx.x >> 6);
  int l = threadIdx.x & 63;
  if (wid >= N) return;
  int q2 = l >> 1, lc2 = l & 1;
  int fo = slice * 16 + lc2 * 8;
  const ushort* Xs = Xb + fo;
  float acc[8] = {0.f, 0.f, 0.f, 0.f, 0.f, 0.f, 0.f, 0.f};
  int s0 = rowptr[wid], s1 = rowptr[wid + 1];
#define WEIGHT(ix) (0x3F80u)
  AGG_SLICE_LOOP(Xs)
#undef WEIGHT
  if (q2 == 0) {
    int deg = s1 - s0;
    float inv = 1.f / (float)(deg > 0 ? deg : 1);
    uint4 r = make_uint4(cvtpk(acc[0] * inv, acc[1] * inv),
                         cvtpk(acc[2] * inv, acc[3] * inv),
                         cvtpk(acc[4] * inv, acc[5] * inv),
                         cvtpk(acc[6] * inv, acc[7] * inv));
    *(uint4*)&Mb[(size_t)wid * 128 + fo] = r;
  }
}

// ================= launch =================

extern "C" void kernel_launch(void* const* d_in, const int* in_sizes, int n_in,
                              void* d_out, int out_size, void* d_ws, size_t ws_size,
                              hipStream_t stream) {
  const float* feat = (const float*)d_in[0];
  const int* ei     = (const int*)d_in[1];
  const float* W1   = (const float*)d_in[2];
  const float* b1   = (const float*)d_in[3];
  const float* Wl   = (const float*)d_in[4];
  const float* bl   = (const float*)d_in[5];
  const float* Wr   = (const float*)d_in[6];
  float* out = (float*)d_out;

  int N = in_sizes[0] / 128;
  int E = in_sizes[1] / 2;

  char* ws = (char*)d_ws;
  size_t off = 0;
  auto alloc = [&](size_t bytes) {
    void* p = ws + off;
    off += (bytes + 255) & ~(size_t)255;
    return p;
  };
  ushort* Hb    = (ushort*)alloc((size_t)N * 128 * 2);  // h bf16; reused as mean
  ushort* X1b   = (ushort*)alloc((size_t)N * 128 * 2);  // layer-1 output bf16
  int*   rowptr = (int*)alloc((size_t)(N + 1) * 4);
  float* dinv   = (float*)alloc((size_t)N * 4);
  ushort* dinvb = (ushort*)alloc((size_t)N * 2);
  int*   col    = (int*)alloc((size_t)E * 4);
  int*   counts = (int*)alloc(128 * 256 * 4);  // per-block bucket histograms (NBLK<=128)
  int*   bbase  = (int*)alloc(1024);
  int*   btot   = (int*)alloc(1024);
  // keyval packs alias Hb: dead before k_gemm1 writes Hb
  uint* keyval = (uint*)Hb;

  int NB = (N + 1023) >> 10;          // buckets of 1024 nodes (<=256)
  int NBLK = (E + 16383) / 16384;     // edge chunks (<=128)

  k_hist1<<<NBLK, 256, 0, stream>>>(ei + E, counts, E);
  k_colscan<<<1, 256, 0, stream>>>(counts, bbase, btot, rowptr, NBLK, N, E);
  k_scatter<<<NBLK, 256, 0, stream>>>(ei, counts, bbase, keyval, E);
  k_build<<<NB, 1024, 0, stream>>>(keyval, bbase, btot, rowptr, dinv, dinvb, col, N);

  int gb = (N + 255) / 256;
  int ab = ((N + 7) / 8) * 8;  // node-groups x 8 slices
  k_gemm1<<<gb, 256, 0, stream>>>(feat, W1, Hb, N);
  k_agg_gcn_s<<<ab, 512, 0, stream>>>(Hb, rowptr, col, dinv, dinvb, b1, X1b, N);
  k_agg_mean_s<<<ab, 512, 0, stream>>>(X1b, rowptr, col, Hb, N);
  k_gemm2<<<gb, 256, 0, stream>>>(Hb, X1b, Wl, Wr, bl, out, N);
}

// Round 10
// 206.645 us; speedup vs baseline: 3.7020x; 3.7020x over previous
//
#include <hip/hip_runtime.h>

typedef unsigned int uint;
typedef unsigned short ushort;
typedef short sv8 __attribute__((ext_vector_type(8)));     // 8 bf16 (4 VGPR)
typedef float f32x4 __attribute__((ext_vector_type(4)));
typedef ushort u16x8 __attribute__((ext_vector_type(8)));

__device__ __forceinline__ ushort f2b(float f) {  // fp32 -> bf16 RN (scalar path)
  uint u = __float_as_uint(f);
  return (ushort)((u + 0x7FFFu + ((u >> 16) & 1u)) >> 16);
}
__device__ __forceinline__ float b2f_lo(uint p) { return __uint_as_float(p << 16); }
__device__ __forceinline__ float b2f_hi(uint p) { return __uint_as_float(p & 0xFFFF0000u); }
__device__ __forceinline__ uint cvtpk(float lo, float hi) {  // packed f32->bf16x2 RNE
  uint r;
  asm("v_cvt_pk_bf16_f32 %0, %1, %2" : "=v"(r) : "v"(lo), "v"(hi));
  return r;
}

#define MFMA16(acc, a, b) \
  asm volatile("v_mfma_f32_16x16x32_bf16 %0, %1, %2, %0" : "+v"(acc) : "v"(a), "v"(b))
// acc += p.lo*d.lo + p.hi*d.hi  (bf16 pairs, fp32 accumulate)
#define DOT2(acc, p, d) \
  asm("v_dot2_f32_bf16 %0, %1, %2, %0" : "+v"(acc) : "v"(p), "v"(d))

// 16-row gather step: 4 independent row-pair loads in flight.
// packed = src_idx(bits 0..16) | bf16_weight_no-sign(bits 17..31)
// NOTE: all __shfl are unconditional (full-wave) — ds_bpermute returns 0 when
// the SOURCE lane's exec bit is 0 (round-8 lesson).
#define GATHER16(SRC, jj)                                                     \
  {                                                                           \
    uint pa = (uint)__shfl((int)packed, (jj) + q);                            \
    uint pb = (uint)__shfl((int)packed, (jj) + 4 + q);                        \
    uint pc = (uint)__shfl((int)packed, (jj) + 8 + q);                        \
    uint pd = (uint)__shfl((int)packed, (jj) + 12 + q);                       \
    uint4 va = *(const uint4*)&SRC[(size_t)(pa & 0x1FFFFu) * 128 + lc * 8];   \
    uint4 vb = *(const uint4*)&SRC[(size_t)(pb & 0x1FFFFu) * 128 + lc * 8];   \
    uint4 vc = *(const uint4*)&SRC[(size_t)(pc & 0x1FFFFu) * 128 + lc * 8];   \
    uint4 vd = *(const uint4*)&SRC[(size_t)(pd & 0x1FFFFu) * 128 + lc * 8];   \
    uint dab = (pa >> 17) | ((pb >> 17) << 16);                               \
    uint dcd = (pc >> 17) | ((pd >> 17) << 16);                               \
    uint p;                                                                   \
    p = __builtin_amdgcn_perm(va.x, vb.x, 0x01000504u); DOT2(acc[0], p, dab); \
    p = __builtin_amdgcn_perm(va.x, vb.x, 0x03020706u); DOT2(acc[1], p, dab); \
    p = __builtin_amdgcn_perm(va.y, vb.y, 0x01000504u); DOT2(acc[2], p, dab); \
    p = __builtin_amdgcn_perm(va.y, vb.y, 0x03020706u); DOT2(acc[3], p, dab); \
    p = __builtin_amdgcn_perm(va.z, vb.z, 0x01000504u); DOT2(acc[4], p, dab); \
    p = __builtin_amdgcn_perm(va.z, vb.z, 0x03020706u); DOT2(acc[5], p, dab); \
    p = __builtin_amdgcn_perm(va.w, vb.w, 0x01000504u); DOT2(acc[6], p, dab); \
    p = __builtin_amdgcn_perm(va.w, vb.w, 0x03020706u); DOT2(acc[7], p, dab); \
    p = __builtin_amdgcn_perm(vc.x, vd.x, 0x01000504u); DOT2(acc[0], p, dcd); \
    p = __builtin_amdgcn_perm(vc.x, vd.x, 0x03020706u); DOT2(acc[1], p, dcd); \
    p = __builtin_amdgcn_perm(vc.y, vd.y, 0x01000504u); DOT2(acc[2], p, dcd); \
    p = __builtin_amdgcn_perm(vc.y, vd.y, 0x03020706u); DOT2(acc[3], p, dcd); \
    p = __builtin_amdgcn_perm(vc.z, vd.z, 0x01000504u); DOT2(acc[4], p, dcd); \
    p = __builtin_amdgcn_perm(vc.z, vd.z, 0x03020706u); DOT2(acc[5], p, dcd); \
    p = __builtin_amdgcn_perm(vc.w, vd.w, 0x01000504u); DOT2(acc[6], p, dcd); \
    p = __builtin_amdgcn_perm(vc.w, vd.w, 0x03020706u); DOT2(acc[7], p, dcd); \
  }

// ================= bucketed CSR build (single histogram pass) =================
// bucket = dst >> 10 (1024 nodes/bucket). NB <= 256. chunk per block = 16384 edges.

__global__ __launch_bounds__(256) void k_hist1(const int* __restrict__ dst,
                                               int* __restrict__ counts, int E) {
  __shared__ int h[256];
  int t = threadIdx.x;
  h[t] = 0;
  __syncthreads();
#pragma unroll
  for (int i = 0; i < 16; ++i) {
    int idx = blockIdx.x * 16384 + i * 1024 + t * 4;
    if (idx + 4 <= E) {
      int4 d = *(const int4*)&dst[idx];
      atomicAdd(&h[d.x >> 10], 1);
      atomicAdd(&h[d.y >> 10], 1);
      atomicAdd(&h[d.z >> 10], 1);
      atomicAdd(&h[d.w >> 10], 1);
    } else {
      for (int k = 0; k < 4; ++k)
        if (idx + k < E) atomicAdd(&h[dst[idx + k] >> 10], 1);
    }
  }
  __syncthreads();
  counts[blockIdx.x * 256 + t] = h[t];
}

// column scan over blocks (in-place: counts -> per-block exclusive offsets),
// plus bucket bases / totals. One block of 256 threads; thread b owns bucket b.
__global__ __launch_bounds__(256) void k_colscan(int* __restrict__ counts,
                                                 int* __restrict__ bbase,
                                                 int* __restrict__ btot,
                                                 int* __restrict__ rowptr,
                                                 int NBLK, int N, int E) {
  __shared__ int s[256];
  int b = threadIdx.x;
  int run = 0;
#pragma unroll 4
  for (int blk = 0; blk < NBLK; ++blk) {
    int v = counts[blk * 256 + b];
    counts[blk * 256 + b] = run;
    run += v;
  }
  s[b] = run;
  __syncthreads();
  for (int off = 1; off < 256; off <<= 1) {
    int u = (b >= off) ? s[b - off] : 0;
    __syncthreads();
    s[b] += u;
    __syncthreads();
  }
  bbase[b] = s[b] - run;
  btot[b] = run;
  if (b == 0) rowptr[N] = E;
}

// keyval packing: src(bits 0..16) | (dst & 1023)(bits 17..26)  [N < 131072]
__global__ __launch_bounds__(256) void k_scatter(const int* __restrict__ ei,
                                                 const int* __restrict__ counts,
                                                 const int* __restrict__ bbase,
                                                 uint* __restrict__ keyval, int E) {
  __shared__ int h[256];
  __shared__ int base[256];
  int t = threadIdx.x;
  base[t] = bbase[t] + counts[blockIdx.x * 256 + t];
  h[t] = 0;
  __syncthreads();
#pragma unroll
  for (int i = 0; i < 16; ++i) {
    int idx = blockIdx.x * 16384 + i * 1024 + t * 4;
    if (idx + 4 <= E) {
      int4 sv = *(const int4*)&ei[idx];
      int4 dv = *(const int4*)&ei[E + idx];
      int b0 = dv.x >> 10, b1 = dv.y >> 10, b2 = dv.z >> 10, b3 = dv.w >> 10;
      int r0 = atomicAdd(&h[b0], 1);
      keyval[base[b0] + r0] = (uint)sv.x | (((uint)dv.x & 1023u) << 17);
      int r1 = atomicAdd(&h[b1], 1);
      keyval[base[b1] + r1] = (uint)sv.y | (((uint)dv.y & 1023u) << 17);
      int r2 = atomicAdd(&h[b2], 1);
      keyval[base[b2] + r2] = (uint)sv.z | (((uint)dv.z & 1023u) << 17);
      int r3 = atomicAdd(&h[b3], 1);
      keyval[base[b3] + r3] = (uint)sv.w | (((uint)dv.w & 1023u) << 17);
    } else {
      for (int k = 0; k < 4; ++k)
        if (idx + k < E) {
          int sv = ei[idx + k], dv = ei[E + idx + k];
          int b = dv >> 10;
          int r = atomicAdd(&h[b], 1);
          keyval[base[b] + r] = (uint)sv | (((uint)dv & 1023u) << 17);
        }
    }
  }
}

// one block per bucket: per-node counts, local scan, rowptr/dinv(f32+bf16), col scatter
__global__ __launch_bounds__(1024) void k_build(const uint* __restrict__ keyval,
                                                const int* __restrict__ bbase,
                                                const int* __restrict__ btot,
                                                int* __restrict__ rowptr,
                                                float* __restrict__ dinv,
                                                ushort* __restrict__ dinvb,
                                                int* __restrict__ col, int N) {
  __shared__ int c[1024];
  int b = blockIdx.x, t = threadIdx.x;
  int ebase = bbase[b], ecnt = btot[b];
  int node0 = b << 10;
  c[t] = 0;
  __syncthreads();
  for (int i = t; i < ecnt; i += 1024)
    atomicAdd(&c[keyval[ebase + i] >> 17], 1);
  __syncthreads();
  int v = c[t];
  for (int off = 1; off < 1024; off <<= 1) {
    int u = (t >= off) ? c[t - off] : 0;
    __syncthreads();
    c[t] += u;
    __syncthreads();
  }
  int excl = c[t] - v;
  int node = node0 + t;
  if (node < N) {
    float dv = rsqrtf((float)(v + 1));  // GCN degree incl self-loop
    rowptr[node] = ebase + excl;
    dinv[node] = dv;
    dinvb[node] = f2b(dv);
  }
  __syncthreads();
  c[t] = excl;
  __syncthreads();
  for (int i = t; i < ecnt; i += 1024) {
    uint kv = keyval[ebase + i];
    int r = atomicAdd(&c[kv >> 17], 1);
    col[ebase + r] = (int)(kv & 0x1FFFFu);
  }
}

// ====== GEMM1: Hb(bf16) = feat(fp32) @ W1^T; 256 rows/block, 64 rows/wave ======

__global__ __launch_bounds__(256) void k_gemm1(const float* __restrict__ A,
                                               const float* __restrict__ W,
                                               ushort* __restrict__ Hb, int N) {
  __shared__ __align__(16) ushort smem[17408];  // W tile 32KB; epilogue 4x[16][136]
  int t = threadIdx.x;
#pragma unroll
  for (int i = 0; i < 8; ++i) {
    int c_ = t + i * 256;
    int row = c_ >> 4, slot = c_ & 15;
    const float* wp = &W[row * 128 + slot * 8];
    float4 w0 = *(const float4*)wp;
    float4 w1 = *(const float4*)(wp + 4);
    uint4 v = make_uint4(cvtpk(w0.x, w0.y), cvtpk(w0.z, w0.w),
                         cvtpk(w1.x, w1.y), cvtpk(w1.z, w1.w));
    *(uint4*)&smem[row * 128 + ((slot ^ (row & 7)) << 3)] = v;
  }
  __syncthreads();

  int wv = t >> 6, l = t & 63;
  int lr = l & 15, lk = l >> 4;
  int r0 = blockIdx.x * 256 + wv * 64;
  f32x4 acc[4][8];
#pragma unroll
  for (int rb = 0; rb < 4; ++rb)
#pragma unroll
    for (int ct = 0; ct < 8; ++ct) acc[rb][ct] = (f32x4){0.f, 0.f, 0.f, 0.f};

#pragma unroll
  for (int kk = 0; kk < 4; ++kk) {
    sv8 af[4];
#pragma unroll
    for (int rb = 0; rb < 4; ++rb) {
      int r = r0 + rb * 16 + lr;
      if (r >= N) r = N - 1;
      const float* ap = &A[(size_t)r * 128 + kk * 32 + lk * 8];
      float4 a0 = *(const float4*)ap;
      float4 a1 = *(const float4*)(ap + 4);
      uint4 au = make_uint4(cvtpk(a0.x, a0.y), cvtpk(a0.z, a0.w),
                            cvtpk(a1.x, a1.y), cvtpk(a1.z, a1.w));
      af[rb] = *(sv8*)&au;
    }
#pragma unroll
    for (int ct = 0; ct < 8; ++ct) {
      int brow = ct * 16 + lr;
      sv8 bf = *(const sv8*)&smem[brow * 128 + (((kk * 4 + lk) ^ (brow & 7)) << 3)];
      MFMA16(acc[0][ct], af[0], bf);
      MFMA16(acc[1][ct], af[1], bf);
      MFMA16(acc[2][ct], af[2], bf);
      MFMA16(acc[3][ct], af[3], bf);
    }
  }
  asm volatile("s_nop 7\n\ts_nop 7");
  __syncthreads();  // protect W tile until all waves done
  ushort* ep = smem + wv * (16 * 136);
#pragma unroll
  for (int rb = 0; rb < 4; ++rb) {
#pragma unroll
    for (int ct = 0; ct < 8; ++ct)
#pragma unroll
      for (int i = 0; i < 4; ++i)
        ep[(lk * 4 + i) * 136 + ct * 16 + lr] = f2b(acc[rb][ct][i]);
#pragma unroll
    for (int it = 0; it < 2; ++it) {
      int row = it * 8 + (l >> 3);
      int gr = r0 + rb * 16 + row;
      if (gr < N) {
#pragma unroll
        for (int cc = 0; cc < 2; ++cc) {
          int colv = cc * 64 + (l & 7) * 8;
          *(u16x8*)&Hb[(size_t)gr * 128 + colv] = *(const u16x8*)&ep[row * 136 + colv];
        }
      }
    }
  }
}

// == GEMM2: Out = relu(mean@Wl^T + x1@Wr^T + bl); 256 rows/block, 64 rows/wave ==

__global__ __launch_bounds__(256) void k_gemm2(const ushort* __restrict__ Mb,
                                               const ushort* __restrict__ X1b,
                                               const float* __restrict__ Wl,
                                               const float* __restrict__ Wr,
                                               const float* __restrict__ bl,
                                               float* __restrict__ Out, int N) {
  __shared__ __align__(16) ushort smem[2 * 128 * 128];  // 64KB; epilogue reuses 33.8KB
  int t = threadIdx.x;
#pragma unroll
  for (int i = 0; i < 8; ++i) {
    int c_ = t + i * 256;
    int row = c_ >> 4, slot = c_ & 15;
    int off = (slot ^ (row & 7)) << 3;
    {
      const float* wp = &Wl[row * 128 + slot * 8];
      float4 w0 = *(const float4*)wp;
      float4 w1 = *(const float4*)(wp + 4);
      *(uint4*)&smem[row * 128 + off] =
          make_uint4(cvtpk(w0.x, w0.y), cvtpk(w0.z, w0.w),
                     cvtpk(w1.x, w1.y), cvtpk(w1.z, w1.w));
    }
    {
      const float* wp = &Wr[row * 128 + slot * 8];
      float4 w0 = *(const float4*)wp;
      float4 w1 = *(const float4*)(wp + 4);
      *(uint4*)&smem[16384 + row * 128 + off] =
          make_uint4(cvtpk(w0.x, w0.y), cvtpk(w0.z, w0.w),
                     cvtpk(w1.x, w1.y), cvtpk(w1.z, w1.w));
    }
  }
  __syncthreads();

  int wv = t >> 6, l = t & 63;
  int lr = l & 15, lk = l >> 4;
  int r0 = blockIdx.x * 256 + wv * 64;
  f32x4 acc[4][8];
#pragma unroll
  for (int rb = 0; rb < 4; ++rb)
#pragma unroll
    for (int ct = 0; ct < 8; ++ct) acc[rb][ct] = (f32x4){0.f, 0.f, 0.f, 0.f};

#pragma unroll
  for (int ph = 0; ph < 2; ++ph) {
    const ushort* Ab = ph ? X1b : Mb;
    const ushort* Wp = smem + ph * 16384;
#pragma unroll
    for (int kk = 0; kk < 4; ++kk) {
      sv8 af[4];
#pragma unroll
      for (int rb = 0; rb < 4; ++rb) {
        int r = r0 + rb * 16 + lr;
        if (r >= N) r = N - 1;
        af[rb] = *(const sv8*)&Ab[(size_t)r * 128 + kk * 32 + lk * 8];
      }
#pragma unroll
      for (int ct = 0; ct < 8; ++ct) {
        int brow = ct * 16 + lr;
        sv8 bf = *(const sv8*)&Wp[brow * 128 + (((kk * 4 + lk) ^ (brow & 7)) << 3)];
        MFMA16(acc[0][ct], af[0], bf);
        MFMA16(acc[1][ct], af[1], bf);
        MFMA16(acc[2][ct], af[2], bf);
        MFMA16(acc[3][ct], af[3], bf);
      }
    }
  }
  asm volatile("s_nop 7\n\ts_nop 7");
  __syncthreads();
  float* epf = (float*)smem + wv * (16 * 132);
  float bb[8];
#pragma unroll
  for (int ct = 0; ct < 8; ++ct) bb[ct] = bl[ct * 16 + lr];
#pragma unroll
  for (int rb = 0; rb < 4; ++rb) {
#pragma unroll
    for (int ct = 0; ct < 8; ++ct)
#pragma unroll
      for (int i = 0; i < 4; ++i)
        epf[(lk * 4 + i) * 132 + ct * 16 + lr] = fmaxf(acc[rb][ct][i] + bb[ct], 0.f);
#pragma unroll
    for (int it = 0; it < 2; ++it) {
      int row = it * 8 + (l >> 3);
      int gr = r0 + rb * 16 + row;
      if (gr < N) {
#pragma unroll
        for (int cc = 0; cc < 4; ++cc) {
          int colv = cc * 32 + (l & 7) * 4;
          *(float4*)&Out[(size_t)gr * 128 + colv] = *(const float4*)&epf[row * 132 + colv];
        }
      }
    }
  }
}

// ========== aggregations: wave/node, 16 rows/iter, 4 uint4 loads in flight ==========

__global__ __launch_bounds__(256) void k_agg_gcn(const ushort* __restrict__ Hb,
                                                 const int* __restrict__ rowptr,
                                                 const int* __restrict__ col,
                                                 const float* __restrict__ dinv,
                                                 const ushort* __restrict__ dinvb,
                                                 const float* __restrict__ bias,
                                                 ushort* __restrict__ X1b, int N) {
  int wid = (blockIdx.x * 256 + threadIdx.x) >> 6;
  int l = threadIdx.x & 63;
  if (wid >= N) return;
  int q = l >> 4, lc = l & 15;
  float di = dinv[wid];
  float acc[8] = {0.f, 0.f, 0.f, 0.f, 0.f, 0.f, 0.f, 0.f};
  int s0 = rowptr[wid], s1 = rowptr[wid + 1];
  for (int j0 = s0; j0 < s1; j0 += 64) {
    int rem = s1 - j0;
    uint packed = 0;
    if (l < rem) {
      int ix = col[j0 + l];
      packed = (uint)ix | ((uint)dinvb[ix] << 17);  // dinv>0 -> bf16 sign bit 0
    }
    int m = rem < 64 ? rem : 64;
    for (int jj = 0; jj < m; jj += 16) GATHER16(Hb, jj);
  }
#pragma unroll
  for (int k = 0; k < 8; ++k) {
    acc[k] += __shfl_xor(acc[k], 16);
    acc[k] += __shfl_xor(acc[k], 32);
  }
  if (q == 0) {
    uint4 hv = *(const uint4*)&Hb[(size_t)wid * 128 + lc * 8];
    float4 b0 = *(const float4*)&bias[lc * 8];
    float4 b1 = *(const float4*)&bias[lc * 8 + 4];
    float hvf[8] = {b2f_lo(hv.x), b2f_hi(hv.x), b2f_lo(hv.y), b2f_hi(hv.y),
                    b2f_lo(hv.z), b2f_hi(hv.z), b2f_lo(hv.w), b2f_hi(hv.w)};
    float bb[8] = {b0.x, b0.y, b0.z, b0.w, b1.x, b1.y, b1.z, b1.w};
    float o[8];
#pragma unroll
    for (int k = 0; k < 8; ++k)
      o[k] = fmaxf((acc[k] + hvf[k] * di) * di + bb[k], 0.f);
    uint4 r = make_uint4(cvtpk(o[0], o[1]), cvtpk(o[2], o[3]),
                         cvtpk(o[4], o[5]), cvtpk(o[6], o[7]));
    *(uint4*)&X1b[(size_t)wid * 128 + lc * 8] = r;
  }
}

__global__ __launch_bounds__(256) void k_agg_mean(const ushort* __restrict__ Xb,
                                                  const int* __restrict__ rowptr,
                                                  const int* __restrict__ col,
                                                  ushort* __restrict__ Mb, int N) {
  int wid = (blockIdx.x * 256 + threadIdx.x) >> 6;
  int l = threadIdx.x & 63;
  if (wid >= N) return;
  int q = l >> 4, lc = l & 15;
  float acc[8] = {0.f, 0.f, 0.f, 0.f, 0.f, 0.f, 0.f, 0.f};
  int s0 = rowptr[wid], s1 = rowptr[wid + 1];
  for (int j0 = s0; j0 < s1; j0 += 64) {
    int rem = s1 - j0;
    uint packed = 0;
    if (l < rem) packed = (uint)col[j0 + l] | (0x3F80u << 17);  // weight bf16 1.0
    int m = rem < 64 ? rem : 64;
    for (int jj = 0; jj < m; jj += 16) GATHER16(Xb, jj);
  }
#pragma unroll
  for (int k = 0; k < 8; ++k) {
    acc[k] += __shfl_xor(acc[k], 16);
    acc[k] += __shfl_xor(acc[k], 32);
  }
  if (q == 0) {
    int deg = s1 - s0;
    float inv = 1.f / (float)(deg > 0 ? deg : 1);
    uint4 r = make_uint4(cvtpk(acc[0] * inv, acc[1] * inv),
                         cvtpk(acc[2] * inv, acc[3] * inv),
                         cvtpk(acc[4] * inv, acc[5] * inv),
                         cvtpk(acc[6] * inv, acc[7] * inv));
    *(uint4*)&Mb[(size_t)wid * 128 + lc * 8] = r;
  }
}

// ================= launch =================

extern "C" void kernel_launch(void* const* d_in, const int* in_sizes, int n_in,
                              void* d_out, int out_size, void* d_ws, size_t ws_size,
                              hipStream_t stream) {
  const float* feat = (const float*)d_in[0];
  const int* ei     = (const int*)d_in[1];
  const float* W1   = (const float*)d_in[2];
  const float* b1   = (const float*)d_in[3];
  const float* Wl   = (const float*)d_in[4];
  const float* bl   = (const float*)d_in[5];
  const float* Wr   = (const float*)d_in[6];
  float* out = (float*)d_out;

  int N = in_sizes[0] / 128;
  int E = in_sizes[1] / 2;

  char* ws = (char*)d_ws;
  size_t off = 0;
  auto alloc = [&](size_t bytes) {
    void* p = ws + off;
    off += (bytes + 255) & ~(size_t)255;
    return p;
  };
  ushort* Hb    = (ushort*)alloc((size_t)N * 128 * 2);  // h bf16; reused as mean
  ushort* X1b   = (ushort*)alloc((size_t)N * 128 * 2);  // layer-1 output bf16
  int*   rowptr = (int*)alloc((size_t)(N + 1) * 4);
  float* dinv   = (float*)alloc((size_t)N * 4);
  ushort* dinvb = (ushort*)alloc((size_t)N * 2);
  int*   col    = (int*)alloc((size_t)E * 4);
  int*   counts = (int*)alloc(128 * 256 * 4);  // per-block bucket histograms (NBLK<=128)
  int*   bbase  = (int*)alloc(1024);
  int*   btot   = (int*)alloc(1024);
  // keyval packs alias Hb: dead before k_gemm1 writes Hb
  uint* keyval = (uint*)Hb;

  int NB = (N + 1023) >> 10;          // buckets of 1024 nodes (<=256)
  int NBLK = (E + 16383) / 16384;     // edge chunks (<=128)

  k_hist1<<<NBLK, 256, 0, stream>>>(ei + E, counts, E);
  k_colscan<<<1, 256, 0, stream>>>(counts, bbase, btot, rowptr, NBLK, N, E);
  k_scatter<<<NBLK, 256, 0, stream>>>(ei, counts, bbase, keyval, E);
  k_build<<<NB, 1024, 0, stream>>>(keyval, bbase, btot, rowptr, dinv, dinvb, col, N);

  int gb = (N + 255) / 256;
  k_gemm1<<<gb, 256, 0, stream>>>(feat, W1, Hb, N);
  k_agg_gcn<<<(N + 3) / 4, 256, 0, stream>>>(Hb, rowptr, col, dinv, dinvb, b1, X1b, N);
  k_agg_mean<<<(N + 3) / 4, 256, 0, stream>>>(X1b, rowptr, col, Hb, N);
  k_gemm2<<<gb, 256, 0, stream>>>(Hb, X1b, Wl, Wr, bl, out, N);
}